// Round 1
// baseline (424.387 us; speedup 1.0000x reference)
//
#include <hip/hip_runtime.h>
#include <cstdint>
#include <cstddef>

#define LN_EPS 1e-5f

typedef short bf16x8 __attribute__((ext_vector_type(8)));
typedef float f32x4 __attribute__((ext_vector_type(4)));

__device__ __forceinline__ uint16_t f2bf(float f){
  uint32_t u = __float_as_uint(f);
  u += 0x7fffu + ((u >> 16) & 1u);
  return (uint16_t)(u >> 16);
}
__device__ __forceinline__ float bf2f(uint16_t h){
  return __uint_as_float(((uint32_t)h) << 16);
}
__device__ __forceinline__ float sigm(float x){ return 1.0f/(1.0f + __expf(-x)); }

// ---------------- K0: convert 6 weight matrices (128x128 fp32) to bf16 ----------------
// order: 0=left_proj_w 1=left_gate_w 2=right_proj_w 3=right_gate_w 4=gating_w 5=out_proj_w
__global__ __launch_bounds__(256) void wconv_k(
    const float* __restrict__ w0, const float* __restrict__ w1,
    const float* __restrict__ w2, const float* __restrict__ w3,
    const float* __restrict__ w4, const float* __restrict__ w5,
    uint16_t* __restrict__ dst)
{
  int i = blockIdx.x*256 + threadIdx.x;   // 6*16384 total
  int m = i >> 14, e = i & 16383;
  const float* s = (m==0)?w0:(m==1)?w1:(m==2)?w2:(m==3)?w3:(m==4)?w4:w5;
  dst[i] = f2bf(s[e]);
}

// ---------------- K1: LN + 5 projections, fused epilogues ----------------
// grid 4096 blocks of 256 threads; each block owns 64 positions (rows of [M=262144, C=128]).
// outputs: leftT/rightT in [C][N][N] bf16 (c-major, transposed via LDS), g in [N][N][C] bf16.
__global__ __launch_bounds__(256) void k1_proj(
    const float* __restrict__ act, const float* __restrict__ mask,
    const float* __restrict__ lnw, const float* __restrict__ lnb,
    const float* __restrict__ lpb, const float* __restrict__ lgB,
    const float* __restrict__ rpb, const float* __restrict__ rgB,
    const float* __restrict__ gB,
    const uint16_t* __restrict__ wbf,
    uint16_t* __restrict__ leftT, uint16_t* __restrict__ rightT,
    uint16_t* __restrict__ gbuf)
{
  __shared__ uint16_t sA[64*128];   // LN'd a-tile, [row 64][c 128] bf16, swizzled
  __shared__ uint16_t sT[128*64];   // transpose buffer [c 128][p 64] bf16, swizzled
  __shared__ float sMask[64];
  const int t = threadIdx.x;
  const int p0 = blockIdx.x * 64;

  { // ---- LayerNorm (fp32) ----
    const int row = t >> 2, q = t & 3;
    const float* src = act + (size_t)(p0 + row)*128 + q*32;
    float x[32];
#pragma unroll
    for(int u=0;u<8;u++){
      float4 v = *(const float4*)(src + u*4);
      x[u*4+0]=v.x; x[u*4+1]=v.y; x[u*4+2]=v.z; x[u*4+3]=v.w;
    }
    float s=0.f, s2=0.f;
#pragma unroll
    for(int u=0;u<32;u++){ s += x[u]; s2 += x[u]*x[u]; }
    s  += __shfl_xor(s,1);  s  += __shfl_xor(s,2);
    s2 += __shfl_xor(s2,1); s2 += __shfl_xor(s2,2);
    const float mu   = s * (1.f/128.f);
    const float var  = s2 * (1.f/128.f) - mu*mu;
    const float rstd = rsqrtf(var + LN_EPS);
#pragma unroll
    for(int u=0;u<4;u++){
      const int c0 = q*32 + u*8;
      uint16_t h[8];
#pragma unroll
      for(int j=0;j<8;j++)
        h[j] = f2bf((x[u*8+j] - mu)*rstd*lnw[c0+j] + lnb[c0+j]);
      uint4 pk;
      pk.x = (uint32_t)h[0] | ((uint32_t)h[1]<<16);
      pk.y = (uint32_t)h[2] | ((uint32_t)h[3]<<16);
      pk.z = (uint32_t)h[4] | ((uint32_t)h[5]<<16);
      pk.w = (uint32_t)h[6] | ((uint32_t)h[7]<<16);
      const int byte = row*256 + ((c0*2) ^ ((row&7)<<4));
      *(uint4*)((char*)sA + byte) = pk;
    }
    if(t < 64) sMask[t] = mask[p0 + t];
  }
  __syncthreads();

  const int lane = t & 63, wid = t >> 6;
  const int wm = wid >> 1, wn = wid & 1;   // 2x2 wave grid: rows 32, cols 64 per wave
  const int l15 = lane & 15, lh = lane >> 4;
  const f32x4 z4 = {0.f,0.f,0.f,0.f};

  auto gemm = [&](int mat, f32x4 acc[2][4]){
    const uint16_t* W = wbf + mat*16384;
#pragma unroll
    for(int ks=0;ks<4;ks++){
      bf16x8 af[2];
#pragma unroll
      for(int tm=0;tm<2;tm++){
        const int row = wm*32 + tm*16 + l15;
        const int byte = row*256 + ((ks*64 + lh*16) ^ ((row&7)<<4));
        af[tm] = *(const bf16x8*)((const char*)sA + byte);
      }
#pragma unroll
      for(int tn=0;tn<4;tn++){
        const int o = wn*64 + tn*16 + l15;
        const bf16x8 bv = *(const bf16x8*)(W + o*128 + ks*32 + lh*8);
#pragma unroll
        for(int tm=0;tm<2;tm++)
          acc[tm][tn] = __builtin_amdgcn_mfma_f32_16x16x32_bf16(af[tm], bv, acc[tm][tn], 0,0,0);
      }
    }
  };

  auto combine_store = [&](f32x4 aP[2][4], f32x4 aG[2][4],
                           const float* pb, const float* gb2, uint16_t* dstT){
#pragma unroll
    for(int tm=0;tm<2;tm++){
#pragma unroll
      for(int tn=0;tn<4;tn++){
        const int col = wn*64 + tn*16 + l15;
        const float pbv = pb[col], gbv = gb2[col];
#pragma unroll
        for(int r=0;r<4;r++){
          const int row = wm*32 + tm*16 + lh*4 + r;
          const float val = sMask[row]*(aP[tm][tn][r] + pbv) * sigm(aG[tm][tn][r] + gbv);
          const int byte = col*128 + ((row*2) ^ ((col&7)<<3));
          *(uint16_t*)((char*)sT + byte) = f2bf(val);
        }
      }
    }
    __syncthreads();
    { // readout: thread -> (c = t>>1, 32 consecutive p), write [C][N*N] coalesced 64B
      const int c = t >> 1, ph = (t & 1)*32;
      uint32_t d[16];
#pragma unroll
      for(int u=0;u<8;u++){
        const int row = ph + u*4;
        const int byte = c*128 + ((row*2) ^ ((c&7)<<3));
        uint2 v = *(const uint2*)((const char*)sT + byte);
        d[u*2]=v.x; d[u*2+1]=v.y;
      }
      uint16_t* dst = dstT + (size_t)c*262144 + p0 + ph;
      uint4 q0; q0.x=d[0];  q0.y=d[1];  q0.z=d[2];  q0.w=d[3];
      uint4 q1; q1.x=d[4];  q1.y=d[5];  q1.z=d[6];  q1.w=d[7];
      uint4 q2; q2.x=d[8];  q2.y=d[9];  q2.z=d[10]; q2.w=d[11];
      uint4 q3; q3.x=d[12]; q3.y=d[13]; q3.z=d[14]; q3.w=d[15];
      *(uint4*)(dst+ 0)=q0; *(uint4*)(dst+ 8)=q1;
      *(uint4*)(dst+16)=q2; *(uint4*)(dst+24)=q3;
    }
    __syncthreads();
  };

  f32x4 aP[2][4], aG[2][4];
#pragma unroll
  for(int a=0;a<2;a++) for(int b=0;b<4;b++){ aP[a][b]=z4; aG[a][b]=z4; }
  gemm(0, aP);                      // left_proj
  gemm(1, aG);                      // left_gate
  combine_store(aP, aG, lpb, lgB, leftT);

#pragma unroll
  for(int a=0;a<2;a++) for(int b=0;b<4;b++){ aP[a][b]=z4; aG[a][b]=z4; }
  gemm(2, aP);                      // right_proj
  gemm(3, aG);                      // right_gate
  combine_store(aP, aG, rpb, rgB, rightT);

  { // gating for the final output
#pragma unroll
    for(int a=0;a<2;a++) for(int b=0;b<4;b++) aG[a][b]=z4;
    gemm(4, aG);
#pragma unroll
    for(int tm=0;tm<2;tm++){
#pragma unroll
      for(int tn=0;tn<4;tn++){
        const int col = wn*64 + tn*16 + l15;
        const float gbv = gB[col];
#pragma unroll
        for(int r=0;r<4;r++){
          const int row = wm*32 + tm*16 + lh*4 + r;
          gbuf[(size_t)(p0+row)*128 + col] = f2bf(sigm(aG[tm][tn][r] + gbv));
        }
      }
    }
  }
}

// ---------------- K2: triangle einsum, 128 c-batched 512x512x512 GEMMs ----------------
// t_c[i][j] = sum_k L_c[i][k] * R_c[j][k]; blocks: c(128) x it(4) x jt(4); tile 128x128, BK=64.
__global__ __launch_bounds__(256) void k2_tri(
    const uint16_t* __restrict__ leftT, const uint16_t* __restrict__ rightT,
    uint16_t* __restrict__ tbuf)
{
  __shared__ uint16_t sL[128*64];   // [row 128][k 64] bf16, swizzled
  __shared__ uint16_t sR[128*64];
  const int bx = blockIdx.x;
  const int c = bx >> 4, it = (bx >> 2) & 3, jt = bx & 3;
  const uint16_t* L = leftT  + (size_t)c*262144;
  const uint16_t* R = rightT + (size_t)c*262144;
  const int t = threadIdx.x, lane = t & 63, wid = t >> 6;
  const int wm = wid >> 1, wn = wid & 1;   // wave: 64x64 of the 128x128 tile
  const int l15 = lane & 15, lh = lane >> 4;
  const f32x4 z4 = {0.f,0.f,0.f,0.f};
  f32x4 acc[4][4];
#pragma unroll
  for(int a=0;a<4;a++) for(int b=0;b<4;b++) acc[a][b]=z4;

  const int srow = t >> 1, shalf = (t & 1)*64;  // staging: 64B per thread per matrix
  for(int kt=0; kt<8; kt++){
    __syncthreads();
#pragma unroll
    for(int u=0;u<4;u++){
      const int kb = shalf + u*16;                 // byte within the 128B row
      const int ge = kt*64 + (kb >> 1);            // global k element
      const int db = srow*128 + (kb ^ ((srow&7)<<4));
      uint4 va = *(const uint4*)(L + (size_t)(it*128+srow)*512 + ge);
      *(uint4*)((char*)sL + db) = va;
      uint4 vb = *(const uint4*)(R + (size_t)(jt*128+srow)*512 + ge);
      *(uint4*)((char*)sR + db) = vb;
    }
    __syncthreads();
#pragma unroll
    for(int ks=0;ks<2;ks++){
      bf16x8 af[4], bv[4];
#pragma unroll
      for(int tm=0;tm<4;tm++){
        const int row = wm*64 + tm*16 + l15;
        const int byte = row*128 + ((ks*64 + lh*16) ^ ((row&7)<<4));
        af[tm] = *(const bf16x8*)((const char*)sL + byte);
      }
#pragma unroll
      for(int tn=0;tn<4;tn++){
        const int row = wn*64 + tn*16 + l15;
        const int byte = row*128 + ((ks*64 + lh*16) ^ ((row&7)<<4));
        bv[tn] = *(const bf16x8*)((const char*)sR + byte);
      }
#pragma unroll
      for(int tm=0;tm<4;tm++)
#pragma unroll
        for(int tn=0;tn<4;tn++)
          acc[tm][tn] = __builtin_amdgcn_mfma_f32_16x16x32_bf16(af[tm], bv[tn], acc[tm][tn], 0,0,0);
    }
  }
  // epilogue: write t (bf16, c-major)
  uint16_t* T = tbuf + (size_t)c*262144;
#pragma unroll
  for(int tm=0;tm<4;tm++){
#pragma unroll
    for(int tn=0;tn<4;tn++){
      const int j = jt*128 + wn*64 + tn*16 + l15;
#pragma unroll
      for(int r=0;r<4;r++){
        const int i = it*128 + wm*64 + tm*16 + lh*4 + r;
        T[(size_t)i*512 + j] = f2bf(acc[tm][tn][r]);
      }
    }
  }
}

// ---------------- K3: LN_c + out_proj + gating multiply ----------------
// grid 4096: block owns positions (i, j0..j0+63); reads t c-major, writes fp32 out [N,N,C].
__global__ __launch_bounds__(256) void k3_out(
    const uint16_t* __restrict__ tbuf, const uint16_t* __restrict__ gbuf,
    const float* __restrict__ lncw, const float* __restrict__ lncb,
    const uint16_t* __restrict__ wbf, const float* __restrict__ opb,
    float* __restrict__ out)
{
  __shared__ uint16_t sT2[64*128];  // [p 64][c 128] bf16, swizzled
  const int bx = blockIdx.x;
  const int i = bx >> 3, j0 = (bx & 7)*64;
  const int t = threadIdx.x;

  { // transpose-load: thread -> (c = t>>1, 32 consecutive j)
    const int c = t >> 1, ph = (t & 1)*32;
    const uint16_t* src = tbuf + (size_t)c*262144 + (size_t)i*512 + j0 + ph;
    uint16_t e[32];
#pragma unroll
    for(int u=0;u<4;u++){
      uint4 v = *(const uint4*)(src + u*8);
      e[u*8+0]=(uint16_t)(v.x&0xffff); e[u*8+1]=(uint16_t)(v.x>>16);
      e[u*8+2]=(uint16_t)(v.y&0xffff); e[u*8+3]=(uint16_t)(v.y>>16);
      e[u*8+4]=(uint16_t)(v.z&0xffff); e[u*8+5]=(uint16_t)(v.z>>16);
      e[u*8+6]=(uint16_t)(v.w&0xffff); e[u*8+7]=(uint16_t)(v.w>>16);
    }
#pragma unroll
    for(int k2=0;k2<32;k2++){
      const int p = ph + k2;
      const int byte = p*256 + ((c*2) ^ ((p&7)<<4));
      *(uint16_t*)((char*)sT2 + byte) = e[k2];
    }
  }
  __syncthreads();

  const int lane = t & 63, wid = t >> 6;
  { // LayerNorm over c per position row (fp32), 4 lanes per row
    const int row = wid*16 + (lane & 15);
    const int q = lane >> 4;
    float xs[32];
#pragma unroll
    for(int u=0;u<4;u++){
      const int kb = q*64 + u*16;
      const int byte = row*256 + (kb ^ ((row&7)<<4));
      uint4 v = *(const uint4*)((const char*)sT2 + byte);
      xs[u*8+0]=bf2f((uint16_t)(v.x&0xffff)); xs[u*8+1]=bf2f((uint16_t)(v.x>>16));
      xs[u*8+2]=bf2f((uint16_t)(v.y&0xffff)); xs[u*8+3]=bf2f((uint16_t)(v.y>>16));
      xs[u*8+4]=bf2f((uint16_t)(v.z&0xffff)); xs[u*8+5]=bf2f((uint16_t)(v.z>>16));
      xs[u*8+6]=bf2f((uint16_t)(v.w&0xffff)); xs[u*8+7]=bf2f((uint16_t)(v.w>>16));
    }
    float s=0.f, s2=0.f;
#pragma unroll
    for(int u=0;u<32;u++){ s += xs[u]; s2 += xs[u]*xs[u]; }
    s  += __shfl_xor(s,16);  s  += __shfl_xor(s,32);
    s2 += __shfl_xor(s2,16); s2 += __shfl_xor(s2,32);
    const float mu   = s * (1.f/128.f);
    const float var  = s2 * (1.f/128.f) - mu*mu;
    const float rstd = rsqrtf(var + LN_EPS);
#pragma unroll
    for(int u=0;u<4;u++){
      const int kb = q*64 + u*16;
      const int c0 = (kb ^ ((row&7)<<4)) >> 1;    // de-swizzled channel of this 16B block
      uint16_t h[8];
#pragma unroll
      for(int j=0;j<8;j++)
        h[j] = f2bf((xs[u*8+j]-mu)*rstd*lncw[c0+j] + lncb[c0+j]);
      uint4 pk;
      pk.x = (uint32_t)h[0] | ((uint32_t)h[1]<<16);
      pk.y = (uint32_t)h[2] | ((uint32_t)h[3]<<16);
      pk.z = (uint32_t)h[4] | ((uint32_t)h[5]<<16);
      pk.w = (uint32_t)h[6] | ((uint32_t)h[7]<<16);
      const int byte = row*256 + (kb ^ ((row&7)<<4));
      *(uint4*)((char*)sT2 + byte) = pk;
    }
  }
  __syncthreads();

  const int wm = wid >> 1, wn = wid & 1;
  const int l15 = lane & 15, lh = lane >> 4;
  const f32x4 z4 = {0.f,0.f,0.f,0.f};
  const uint16_t* W = wbf + 5*16384;   // out_proj_w bf16
  f32x4 acc[2][4];
#pragma unroll
  for(int a=0;a<2;a++) for(int b=0;b<4;b++) acc[a][b]=z4;
#pragma unroll
  for(int ks=0;ks<4;ks++){
    bf16x8 af[2];
#pragma unroll
    for(int tm=0;tm<2;tm++){
      const int row = wm*32 + tm*16 + l15;
      const int byte = row*256 + ((ks*64 + lh*16) ^ ((row&7)<<4));
      af[tm] = *(const bf16x8*)((const char*)sT2 + byte);
    }
#pragma unroll
    for(int tn=0;tn<4;tn++){
      const int o = wn*64 + tn*16 + l15;
      const bf16x8 bv = *(const bf16x8*)(W + o*128 + ks*32 + lh*8);
#pragma unroll
      for(int tm=0;tm<2;tm++)
        acc[tm][tn] = __builtin_amdgcn_mfma_f32_16x16x32_bf16(af[tm], bv, acc[tm][tn], 0,0,0);
    }
  }
  const int pbase = i*512 + j0;
#pragma unroll
  for(int tm=0;tm<2;tm++){
#pragma unroll
    for(int tn=0;tn<4;tn++){
      const int col = wn*64 + tn*16 + l15;
      const float obv = opb[col];
#pragma unroll
      for(int r=0;r<4;r++){
        const int row = wm*32 + tm*16 + lh*4 + r;
        const size_t p = (size_t)(pbase + row);
        const float gv = bf2f(gbuf[p*128 + col]);
        out[p*128 + col] = (acc[tm][tn][r] + obv) * gv;
      }
    }
  }
}

// ---------------- launch ----------------
extern "C" void kernel_launch(void* const* d_in, const int* in_sizes, int n_in,
                              void* d_out, int out_size, void* d_ws, size_t ws_size,
                              hipStream_t stream)
{
  (void)in_sizes; (void)n_in; (void)out_size; (void)ws_size;
  const float* act   = (const float*)d_in[0];
  const float* mask  = (const float*)d_in[1];
  const float* lnw   = (const float*)d_in[2];
  const float* lnb   = (const float*)d_in[3];
  const float* lpw   = (const float*)d_in[4];
  const float* lpb   = (const float*)d_in[5];
  const float* rpw   = (const float*)d_in[6];
  const float* rpb   = (const float*)d_in[7];
  const float* lgw   = (const float*)d_in[8];
  const float* lgb   = (const float*)d_in[9];
  const float* rgw   = (const float*)d_in[10];
  const float* rgb   = (const float*)d_in[11];
  const float* lncw  = (const float*)d_in[12];
  const float* lncb  = (const float*)d_in[13];
  const float* opw   = (const float*)d_in[14];
  const float* opb   = (const float*)d_in[15];
  const float* gw    = (const float*)d_in[16];
  const float* gb    = (const float*)d_in[17];

  char* ws = (char*)d_ws;
  uint16_t* leftT  = (uint16_t*)(ws);                      // 64MB [C][N][N] bf16
  uint16_t* rightT = (uint16_t*)(ws + ((size_t)64<<20));   // 64MB
  uint16_t* gbuf   = (uint16_t*)(ws + ((size_t)128<<20));  // 64MB [N][N][C] bf16
  uint16_t* tbuf   = (uint16_t*)(ws + ((size_t)192<<20));  // 64MB [C][N][N] bf16
  uint16_t* wbf    = (uint16_t*)(ws + ((size_t)256<<20));  // 192KB: 6 bf16 weight mats

  wconv_k<<<384, 256, 0, stream>>>(lpw, lgw, rpw, rgw, gw, opw, wbf);
  k1_proj<<<4096, 256, 0, stream>>>(act, mask, lnw, lnb, lpb, lgb, rpb, rgb, gb,
                                    wbf, leftT, rightT, gbuf);
  k2_tri<<<2048, 256, 0, stream>>>(leftT, rightT, tbuf);
  k3_out<<<4096, 256, 0, stream>>>(tbuf, gbuf, lncw, lncb, wbf, opb, (float*)d_out);
}